// Round 12
// baseline (1949.669 us; speedup 1.0000x reference)
//
#include <hip/hip_runtime.h>
#include <stdint.h>

#define H 512
#define B_SZ 1024
#define T_WARM 256
#define NSTEPS 64
#define TOTAL_T (T_WARM + NSTEPS)

#define RPB 16          // rows per team
#define HC 128          // cols per block
#define NTEAM 64        // B_SZ / RPB
#define NCG 4           // H / HC
#define NBLK 256        // NTEAM * NCG == CU count, 1 block/CU
#define NTHR 512        // 8 waves

typedef __attribute__((ext_vector_type(8))) short bf16x8;
typedef __attribute__((ext_vector_type(4))) float f32x4;

union u32x4_bf { uint32_t w[4]; bf16x8 v; };

__device__ __forceinline__ ushort f2bf(float f) {
    uint32_t u = __builtin_bit_cast(uint32_t, f);
    u += 0x7FFFu + ((u >> 16) & 1u);
    return (ushort)(u >> 16);
}
__device__ __forceinline__ float bf2f(ushort h) {
    uint32_t u = ((uint32_t)h) << 16;
    return __builtin_bit_cast(float, u);
}

// Exchange: ONE packed plane, u32 = (bf16_hi << 16) | bf16_lo per column,
// Hb[row*512 + col]. relu => hi sign bit (bit31) is always 0; producers set
// bit31 = tag ((step>>1)&1) so consumers spin on the DATA itself (no flags).
__global__ void prep_kernel(const float* __restrict__ x,
                            const float* __restrict__ W_hh,
                            const float* __restrict__ b_ih,
                            const float* __restrict__ b_hh,
                            ushort* __restrict__ Wh, ushort* __restrict__ Wl,
                            float* __restrict__ bias, float* __restrict__ xT,
                            uint32_t* __restrict__ Hb0, uint32_t* __restrict__ Hb1) {
    int i = blockIdx.x * 512 + threadIdx.x;      // [0, 524288)
    Hb0[i] = 0u;                                  // h(0)=0, tag0 (bit31=0) -> step0 passes
    Hb1[i] = 0x80000000u;                         // tag1: step1 (expects tag0) must wait
    if (i < H * H) {
        float w = W_hh[i];
        ushort hi = f2bf(w);
        float rem = w - bf2f(hi);
        Wh[i] = hi;
        Wl[i] = f2bf(rem);
    }
    if (i < B_SZ * T_WARM) {
        int b = i & (B_SZ - 1), t = i >> 10;
        xT[t * B_SZ + b] = x[b * T_WARM + t];
    }
    if (i < H) bias[i] = b_ih[i] + b_hh[i];
}

__global__ __launch_bounds__(NTHR, 1)
void rnn_kernel(const float* __restrict__ xT,
                const float* __restrict__ W_ih,
                const float* __restrict__ b_fc_p,
                const float* __restrict__ W_fc,
                const ushort* __restrict__ Wh_g,
                const ushort* __restrict__ Wl_g,
                const float* __restrict__ bias_g,
                uint32_t* __restrict__ Hb0, uint32_t* __restrict__ Hb1,
                float* __restrict__ out) {
    __shared__ float pc[2][8 * 8 * 64 * 4];  // ping-pong partials, 2 x 64 KB
    __shared__ float w_fc_s[H];
    __shared__ float w_in_s[HC];
    __shared__ float bias_s[HC];
    __shared__ float ypt[32 * 16];           // y split-K partials [wq][row]
    __shared__ float sy[RPB];

    const int tid = threadIdx.x;
    const int bid = blockIdx.x;
    const int team = bid & (NTEAM - 1);    // members {team,+64,+128,+192} (perf locality only)
    const int cg = bid >> 6;               // 0..3
    const int row0 = team * RPB;
    const int col0 = cg * HC;

    w_fc_s[tid] = W_fc[tid];               // NTHR == H
    if (tid < HC) { w_in_s[tid] = W_ih[col0 + tid]; bias_s[tid] = bias_g[col0 + tid]; }
    const float bfc = b_fc_p[0];

    const int lane = tid & 63;
    const int wv = tid >> 6;               // 0..7 = k-slice id AND epilogue col-tile
    const int n = lane & 15, q = lane >> 4;

    // ---- W register-resident, k-sliced: wave wv holds k-cols [wv*64,+64) x 128 cols ----
    bf16x8 Bh[16], Bl[16];
    {
        const int kb = wv * 64 + q * 8;
        #pragma unroll
        for (int c = 0; c < 8; ++c) {
            const ushort* wh = Wh_g + (col0 + c * 16 + n) * H + kb;
            const ushort* wl = Wl_g + (col0 + c * 16 + n) * H + kb;
            Bh[c * 2 + 0] = *(const bf16x8*)(wh);
            Bh[c * 2 + 1] = *(const bf16x8*)(wh + 32);
            Bl[c * 2 + 0] = *(const bf16x8*)(wl);
            Bl[c * 2 + 1] = *(const bf16x8*)(wl + 32);
        }
    }

    const uint64_t TB = 0x8000000080000000ULL;

    for (int t = 0; t < TOTAL_T; ++t) {
        // x for this step (wave-local; broadcast later via shfl)
        float xv = 0.f;
        if (t < T_WARM && lane < RPB) xv = xT[t * B_SZ + row0 + lane];

        // ---- spin directly on tagged A data (one fabric RT, no flag) ----
        const uint64_t* src = (const uint64_t*)((t & 1) ? Hb1 : Hb0);
        const int base = (row0 + n) * 256 + wv * 32 + q * 4;   // u64 index
        const uint64_t want = ((t >> 1) & 1) ? TB : 0ULL;
        uint64_t d[8];
        for (;;) {
            #pragma unroll
            for (int j = 0; j < 4; ++j)
                d[j] = __hip_atomic_load(src + base + j, __ATOMIC_RELAXED, __HIP_MEMORY_SCOPE_AGENT);
            #pragma unroll
            for (int j = 0; j < 4; ++j)
                d[4 + j] = __hip_atomic_load(src + base + 16 + j, __ATOMIC_RELAXED, __HIP_MEMORY_SCOPE_AGENT);
            uint64_t bad = 0;
            #pragma unroll
            for (int j = 0; j < 8; ++j) bad |= (d[j] ^ want);
            if (__all((bad & TB) == 0)) break;
            __builtin_amdgcn_s_sleep(1);
        }
        #pragma unroll
        for (int j = 0; j < 8; ++j) d[j] &= ~TB;   // strip tags (real sign always 0)

        // ---- unpack to A frags (hi/lo) ----
        u32x4_bf ah[2], al[2];
        #pragma unroll
        for (int ktl = 0; ktl < 2; ++ktl)
            #pragma unroll
            for (int p = 0; p < 4; ++p) {
                uint32_t lo32 = (uint32_t)d[ktl * 4 + p];
                uint32_t hi32 = (uint32_t)(d[ktl * 4 + p] >> 32);
                ah[ktl].w[p] = (lo32 >> 16) | (hi32 & 0xFFFF0000u);
                al[ktl].w[p] = (lo32 & 0xFFFFu) | (hi32 << 16);
            }

        // ---- 48 MFMA: partial C(16x128) over own k-slice ----
        f32x4 acc[8];
        #pragma unroll
        for (int c = 0; c < 8; ++c) acc[c] = (f32x4){0.f, 0.f, 0.f, 0.f};
        #pragma unroll
        for (int ktl = 0; ktl < 2; ++ktl)
            #pragma unroll
            for (int c = 0; c < 8; ++c) {
                acc[c] = __builtin_amdgcn_mfma_f32_16x16x32_bf16(ah[ktl].v, Bh[c * 2 + ktl], acc[c], 0, 0, 0);
                acc[c] = __builtin_amdgcn_mfma_f32_16x16x32_bf16(al[ktl].v, Bh[c * 2 + ktl], acc[c], 0, 0, 0);
                acc[c] = __builtin_amdgcn_mfma_f32_16x16x32_bf16(ah[ktl].v, Bl[c * 2 + ktl], acc[c], 0, 0, 0);
            }

        // ---- publish partials (ping-pong pc) + y split-K partial ----
        float* pcb = pc[t & 1];
        #pragma unroll
        for (int c = 0; c < 8; ++c)
            *(f32x4*)(&pcb[((wv * 8 + c) * 64 + lane) * 4]) = acc[c];
        if (t >= T_WARM) {
            float yp = 0.f;
            #pragma unroll
            for (int ktl = 0; ktl < 2; ++ktl)
                #pragma unroll
                for (int j = 0; j < 8; ++j) {
                    int k = wv * 64 + ktl * 32 + q * 8 + j;
                    yp += (bf2f((ushort)ah[ktl].v[j]) + bf2f((ushort)al[ktl].v[j])) * w_fc_s[k];
                }
            ypt[(wv * 4 + q) * 16 + n] = yp;
        }
        __syncthreads();   // B1: the ONLY barrier on warm steps

        if (t >= T_WARM) {
            if (tid < RPB) {
                float s = bfc;
                #pragma unroll
                for (int g = 0; g < 32; ++g) s += ypt[g * 16 + tid];
                sy[tid] = s;
                if (cg == 0) out[(row0 + tid) * NSTEPS + (t - T_WARM)] = s;
            }
            __syncthreads();   // B1b (rollout only)
        }

        // ---- reduce 8 partials for own col-tile, epilogue, tag, store ----
        f32x4 v = (f32x4){0.f, 0.f, 0.f, 0.f};
        #pragma unroll
        for (int w = 0; w < 8; ++w)
            v += *(const f32x4*)(&pcb[((w * 8 + wv) * 64 + lane) * 4]);

        const int jl = wv * 16 + n;
        const float wi = w_in_s[jl], bj = bias_s[jl];
        uint32_t* dst = ((t & 1) ? Hb0 : Hb1);               // write buffer (t+1)&1
        const uint32_t tagw = (((t + 1) >> 1) & 1) ? 0x80000000u : 0u;
        #pragma unroll
        for (int i = 0; i < 4; ++i) {
            int m = q * 4 + i;                  // C/D: row = quad*4+reg, col = lane&15
            float sv = (t < T_WARM) ? __shfl(xv, m) : sy[m];
            float val = v[i] + sv * wi + bj;
            val = fmaxf(val, 0.f);
            ushort hi = f2bf(val);
            float rem = val - bf2f(hi);
            uint32_t u = (((uint32_t)hi << 16) | (uint32_t)f2bf(rem)) | tagw;
            __hip_atomic_store(dst + (row0 + m) * H + col0 + jl, u,
                               __ATOMIC_RELAXED, __HIP_MEMORY_SCOPE_AGENT);
        }
        // no drain, no flag, no trailing barrier: data is self-tagged
    }
}

extern "C" void kernel_launch(void* const* d_in, const int* in_sizes, int n_in,
                              void* d_out, int out_size, void* d_ws, size_t ws_size,
                              hipStream_t stream) {
    const float* x    = (const float*)d_in[0];
    const float* W_ih = (const float*)d_in[1];
    const float* W_hh = (const float*)d_in[2];
    const float* b_ih = (const float*)d_in[3];
    const float* b_hh = (const float*)d_in[4];
    const float* W_fc = (const float*)d_in[5];
    const float* b_fc = (const float*)d_in[6];
    float* out = (float*)d_out;

    // ws carve (bytes): Wh 512K | Wl 512K | bias 4K | xT 1M | Hb0 2M | Hb1 2M
    uint8_t* w = (uint8_t*)d_ws;
    ushort*   Wh   = (ushort*)(w);
    ushort*   Wl   = (ushort*)(w + 524288);
    float*    bias = (float*)(w + 1048576);
    float*    xT   = (float*)(w + 1052672);
    uint32_t* Hb0  = (uint32_t*)(w + 2101248);
    uint32_t* Hb1  = (uint32_t*)(w + 4198400);

    prep_kernel<<<1024, 512, 0, stream>>>(x, W_hh, b_ih, b_hh, Wh, Wl, bias, xT, Hb0, Hb1);
    rnn_kernel<<<NBLK, NTHR, 0, stream>>>(xT, W_ih, b_fc, W_fc, Wh, Wl, bias, Hb0, Hb1, out);
}

// Round 13
// 1162.910 us; speedup vs baseline: 1.6765x; 1.6765x over previous
//
#include <hip/hip_runtime.h>
#include <stdint.h>

#define H 512
#define B_SZ 1024
#define T_WARM 256
#define NSTEPS 64
#define TOTAL_T (T_WARM + NSTEPS)

#define RPB 16          // rows per team
#define NTEAM 64        // B_SZ / RPB
#define KQN 4           // K-split blocks per team
#define NBLK 256        // NTEAM * KQN == CU count
#define NTHR 512        // 8 waves
#define KSTR 136        // h LDS k-stride (ushorts), 16B-multiple
#define PCSTR 132       // pcs col-stride (floats)
#define PPAR 2097152    // u32 words per parity of P: 64*4*4*2048

typedef __attribute__((ext_vector_type(8))) short bf16x8;
typedef __attribute__((ext_vector_type(4))) float f32x4;

__device__ __forceinline__ ushort f2bf(float f) {
    uint32_t u = __builtin_bit_cast(uint32_t, f);
    u += 0x7FFFu + ((u >> 16) & 1u);
    return (ushort)(u >> 16);
}
__device__ __forceinline__ float bf2f(ushort h) {
    uint32_t u = ((uint32_t)h) << 16;
    return __builtin_bit_cast(float, u);
}
// fixed-point: enc = (int)(p*2^22) + 2^30, bit31 free => arrival tag. dec exact int.
__device__ __forceinline__ uint32_t encfx(float p, uint32_t tagw) {
    return (uint32_t)((int32_t)(p * 4194304.f) + 0x40000000) | tagw;
}
__device__ __forceinline__ int32_t decfx(uint32_t w) {
    return (int32_t)(w & 0x7FFFFFFFu) - 0x40000000;
}

__global__ void prep_kernel(const float* __restrict__ x,
                            const float* __restrict__ W_hh,
                            const float* __restrict__ b_ih,
                            const float* __restrict__ b_hh,
                            ushort* __restrict__ Wh, ushort* __restrict__ Wl,
                            float* __restrict__ bias, float* __restrict__ xT,
                            uint32_t* __restrict__ P, uint32_t* __restrict__ Yp) {
    int i = blockIdx.x * 512 + threadIdx.x;      // [0, 524288)
    #pragma unroll
    for (int j = 0; j < 8; ++j)                   // P: par0 tag0, par1 tag1
        P[j * 524288 + i] = (j < 4) ? 0u : 0x80000000u;
    if (i < 8192) Yp[i] = 0x80000000u;
    if (i < H * H) {
        float w = W_hh[i];
        ushort hi = f2bf(w);
        float rem = w - bf2f(hi);
        Wh[i] = hi;
        Wl[i] = f2bf(rem);
    }
    if (i < B_SZ * T_WARM) {
        int b = i & (B_SZ - 1), t = i >> 10;
        xT[t * B_SZ + b] = x[b * T_WARM + t];
    }
    if (i < H) bias[i] = b_ih[i] + b_hh[i];
}

__global__ __launch_bounds__(NTHR, 1)
void rnn_kernel(const float* __restrict__ xT,
                const float* __restrict__ W_ih,
                const float* __restrict__ b_fc_p,
                const float* __restrict__ W_fc,
                const ushort* __restrict__ Wh_g,
                const ushort* __restrict__ Wl_g,
                const float* __restrict__ bias_g,
                uint32_t* __restrict__ P, uint32_t* __restrict__ Yp,
                float* __restrict__ out) {
    __shared__ ushort h_hi[RPB * KSTR];      // self h cols, bf16-hi  (4.3 KB)
    __shared__ ushort h_lo[RPB * KSTR];
    __shared__ float pcs[RPB * PCSTR];       // self-waves' partial, [row][col] (8.4 KB)
    __shared__ float wfc_s[128], win_s[128], bias_s[128];
    __shared__ float sx[RPB];
    __shared__ uint32_t yw[64];              // y-partials [src*16+row]

    const int tid = threadIdx.x;
    const int bid = blockIdx.x;
    const int team = bid & (NTEAM - 1);
    const int kq = bid >> 6;                 // 0..3: K-slice & finalized col-range
    const int row0 = team * RPB;

    if (tid < 128) {
        wfc_s[tid] = W_fc[kq * 128 + tid];
        win_s[tid] = W_ih[kq * 128 + tid];
        bias_s[tid] = bias_g[kq * 128 + tid];
    }
    const float bfc = b_fc_p[0];
    for (int i = tid; i < RPB * KSTR; i += NTHR) { h_hi[i] = 0; h_lo[i] = 0; }

    const int lane = tid & 63;
    const int wv = tid >> 6;                 // 0..7: output col-tile [wv*64,+64)
    const int n = lane & 15, q = lane >> 4;
    const int dkq = wv >> 1, jh = wv & 1;    // dest block / col-half within dest
    const bool selfw = (dkq == kq);
    const int r = tid >> 5, g = tid & 31;    // reduction/epilogue mapping

    // ---- W register-resident: all 512 cols x k-slice [kq*128,+128) ----
    bf16x8 Bh[16], Bl[16];                   // [c*4 + kt]
    #pragma unroll
    for (int c = 0; c < 4; ++c) {
        const ushort* wh = Wh_g + (wv * 64 + c * 16 + n) * H + kq * 128 + q * 8;
        const ushort* wl = Wl_g + (wv * 64 + c * 16 + n) * H + kq * 128 + q * 8;
        #pragma unroll
        for (int kt = 0; kt < 4; ++kt) {
            Bh[c * 4 + kt] = *(const bf16x8*)(wh + kt * 32);
            Bl[c * 4 + kt] = *(const bf16x8*)(wl + kt * 32);
        }
    }
    // reduction source blocks (the 3 other k-slices)
    int s0 = (kq + 1) & 3, s1 = (kq + 2) & 3, s2 = (kq + 3) & 3;
    const uint64_t TB = 0x8000000080000000ULL;
    __syncthreads();

    for (int t = 0; t < TOTAL_T; ++t) {
        const uint32_t tagw = ((t >> 1) & 1) ? 0x80000000u : 0u;
        uint32_t* Ppar = P + ((t & 1) ? PPAR : 0);

        // x prefetch
        if (t < T_WARM && tid < RPB) sx[tid] = xT[t * B_SZ + row0 + tid];

        // ---- MFMA immediately: A = self h cols from LDS ----
        f32x4 acc[4];
        #pragma unroll
        for (int c = 0; c < 4; ++c) acc[c] = (f32x4){0.f, 0.f, 0.f, 0.f};
        #pragma unroll
        for (int kt = 0; kt < 4; ++kt) {
            bf16x8 ah = *(const bf16x8*)(&h_hi[n * KSTR + kt * 32 + q * 8]);
            bf16x8 al = *(const bf16x8*)(&h_lo[n * KSTR + kt * 32 + q * 8]);
            #pragma unroll
            for (int c = 0; c < 4; ++c) {
                acc[c] = __builtin_amdgcn_mfma_f32_16x16x32_bf16(ah, Bh[c * 4 + kt], acc[c], 0, 0, 0);
                acc[c] = __builtin_amdgcn_mfma_f32_16x16x32_bf16(al, Bh[c * 4 + kt], acc[c], 0, 0, 0);
                acc[c] = __builtin_amdgcn_mfma_f32_16x16x32_bf16(ah, Bl[c * 4 + kt], acc[c], 0, 0, 0);
            }
        }

        // ---- publish partials: remote -> tagged fixed-point u64 stores; self -> pcs LDS ----
        if (selfw) {
            #pragma unroll
            for (int c = 0; c < 4; ++c)
                #pragma unroll
                for (int i = 0; i < 4; ++i)
                    pcs[(q * 4 + i) * PCSTR + jh * 64 + c * 16 + n] = acc[c][i];
        } else if (t > 0) {
            uint32_t* Pd = Ppar + ((team * 4 + dkq) * 4 + kq) * 2048;
            #pragma unroll
            for (int c = 0; c < 4; ++c)
                #pragma unroll
                for (int i = 0; i < 4; ++i) {
                    uint32_t e = encfx(acc[c][i], tagw);
                    uint32_t other = (uint32_t)__shfl_xor((int)e, 1);
                    if ((n & 1) == 0) {
                        int widx = (q * 4 + i) * 128 + jh * 64 + c * 16 + n;
                        uint64_t v = (uint64_t)e | ((uint64_t)other << 32);
                        __hip_atomic_store((uint64_t*)Pd + (widx >> 1), v,
                                           __ATOMIC_RELAXED, __HIP_MEMORY_SCOPE_AGENT);
                    }
                }
        }

        // ---- y-partial poll (rollout): data sent a full step ago ----
        if (t >= T_WARM && tid < 64) {
            const uint32_t* yp = Yp + (((t & 1) * 64 + team) * 4 + (tid >> 4)) * 16 + (tid & 15);
            uint32_t w;
            for (;;) {
                w = __hip_atomic_load(yp, __ATOMIC_RELAXED, __HIP_MEMORY_SCOPE_AGENT);
                if (__all((w & 0x80000000u) == tagw)) break;
                __builtin_amdgcn_s_sleep(1);
            }
            yw[tid] = w;
        }
        __syncthreads();   // B2: pcs/sx/yw ready

        // ---- reduction: spin on own 6 tagged u64 (3 srcs x 16B), exact int sum ----
        int32_t si0 = 0, si1 = 0, si2 = 0, si3 = 0;
        if (t > 0) {
            const uint64_t want = tagw ? TB : 0ULL;
            const uint64_t* pb0 = (const uint64_t*)(Ppar + ((team * 4 + kq) * 4 + s0) * 2048) + r * 64 + g * 2;
            const uint64_t* pb1 = (const uint64_t*)(Ppar + ((team * 4 + kq) * 4 + s1) * 2048) + r * 64 + g * 2;
            const uint64_t* pb2 = (const uint64_t*)(Ppar + ((team * 4 + kq) * 4 + s2) * 2048) + r * 64 + g * 2;
            uint64_t v00, v01, v10, v11, v20, v21;
            for (;;) {
                v00 = __hip_atomic_load(pb0,     __ATOMIC_RELAXED, __HIP_MEMORY_SCOPE_AGENT);
                v01 = __hip_atomic_load(pb0 + 1, __ATOMIC_RELAXED, __HIP_MEMORY_SCOPE_AGENT);
                v10 = __hip_atomic_load(pb1,     __ATOMIC_RELAXED, __HIP_MEMORY_SCOPE_AGENT);
                v11 = __hip_atomic_load(pb1 + 1, __ATOMIC_RELAXED, __HIP_MEMORY_SCOPE_AGENT);
                v20 = __hip_atomic_load(pb2,     __ATOMIC_RELAXED, __HIP_MEMORY_SCOPE_AGENT);
                v21 = __hip_atomic_load(pb2 + 1, __ATOMIC_RELAXED, __HIP_MEMORY_SCOPE_AGENT);
                uint64_t bad = (v00 ^ want) | (v01 ^ want) | (v10 ^ want)
                             | (v11 ^ want) | (v20 ^ want) | (v21 ^ want);
                if (__all((bad & TB) == 0ULL)) break;
                __builtin_amdgcn_s_sleep(1);
            }
            si0 = decfx((uint32_t)v00) + decfx((uint32_t)v10) + decfx((uint32_t)v20);
            si1 = decfx((uint32_t)(v00 >> 32)) + decfx((uint32_t)(v10 >> 32)) + decfx((uint32_t)(v20 >> 32));
            si2 = decfx((uint32_t)v01) + decfx((uint32_t)v11) + decfx((uint32_t)v21);
            si3 = decfx((uint32_t)(v01 >> 32)) + decfx((uint32_t)(v11 >> 32)) + decfx((uint32_t)(v21 >> 32));
        }
        const float SCL = 2.38418579101562e-7f;  // 2^-22

        // ---- epilogue for self cols [kq*128 + g*4 .. +4), row r ----
        f32x4 pv = *(const f32x4*)(&pcs[r * PCSTR + g * 4]);
        float sv;
        if (t < T_WARM) {
            sv = sx[r];
        } else {
            int32_t ys = decfx(yw[r]) + decfx(yw[16 + r]) + decfx(yw[32 + r]) + decfx(yw[48 + r]);
            sv = (float)ys * SCL + bfc;
            if (kq == 0 && g == 0) out[(row0 + r) * NSTEPS + (t - T_WARM)] = sv;
        }
        float val[4];
        val[0] = fmaxf((float)si0 * SCL + pv[0] + sv * win_s[g * 4 + 0] + bias_s[g * 4 + 0], 0.f);
        val[1] = fmaxf((float)si1 * SCL + pv[1] + sv * win_s[g * 4 + 1] + bias_s[g * 4 + 1], 0.f);
        val[2] = fmaxf((float)si2 * SCL + pv[2] + sv * win_s[g * 4 + 2] + bias_s[g * 4 + 2], 0.f);
        val[3] = fmaxf((float)si3 * SCL + pv[3] + sv * win_s[g * 4 + 3] + bias_s[g * 4 + 3], 0.f);

        // h self-cols back to LDS (hi/lo planes), packed u32 writes
        {
            ushort hi0 = f2bf(val[0]), hi1 = f2bf(val[1]), hi2 = f2bf(val[2]), hi3 = f2bf(val[3]);
            ushort lo0 = f2bf(val[0] - bf2f(hi0)), lo1 = f2bf(val[1] - bf2f(hi1));
            ushort lo2 = f2bf(val[2] - bf2f(hi2)), lo3 = f2bf(val[3] - bf2f(hi3));
            uint32_t* ph = (uint32_t*)(&h_hi[r * KSTR + g * 4]);
            uint32_t* pl = (uint32_t*)(&h_lo[r * KSTR + g * 4]);
            ph[0] = (uint32_t)hi0 | ((uint32_t)hi1 << 16);
            ph[1] = (uint32_t)hi2 | ((uint32_t)hi3 << 16);
            pl[0] = (uint32_t)lo0 | ((uint32_t)lo1 << 16);
            pl[1] = (uint32_t)lo2 | ((uint32_t)lo3 << 16);
        }

        // y-partial for NEXT step (rollout pipeline), sent one step ahead of use
        if (t >= T_WARM - 1 && t < TOTAL_T - 1) {
            float yp = val[0] * wfc_s[g * 4 + 0] + val[1] * wfc_s[g * 4 + 1]
                     + val[2] * wfc_s[g * 4 + 2] + val[3] * wfc_s[g * 4 + 3];
            #pragma unroll
            for (int off = 16; off; off >>= 1) yp += __shfl_down(yp, off, 32);
            if (g == 0) {
                uint32_t tagn = (((t + 1) >> 1) & 1) ? 0x80000000u : 0u;
                uint32_t* yd = Yp + ((((t + 1) & 1) * 64 + team) * 4 + kq) * 16 + r;
                __hip_atomic_store(yd, encfx(yp, tagn), __ATOMIC_RELAXED, __HIP_MEMORY_SCOPE_AGENT);
            }
        }
        __syncthreads();   // B1: h(t+1) ready for next step's A-reads
    }
}

extern "C" void kernel_launch(void* const* d_in, const int* in_sizes, int n_in,
                              void* d_out, int out_size, void* d_ws, size_t ws_size,
                              hipStream_t stream) {
    const float* x    = (const float*)d_in[0];
    const float* W_ih = (const float*)d_in[1];
    const float* W_hh = (const float*)d_in[2];
    const float* b_ih = (const float*)d_in[3];
    const float* b_hh = (const float*)d_in[4];
    const float* W_fc = (const float*)d_in[5];
    const float* b_fc = (const float*)d_in[6];
    float* out = (float*)d_out;

    // ws carve (bytes): Wh 512K | Wl 512K | bias 2K+pad | xT 1M | P 16M | Yp 32K  (~18.9 MB)
    uint8_t* w = (uint8_t*)d_ws;
    ushort*   Wh   = (ushort*)(w);
    ushort*   Wl   = (ushort*)(w + 524288);
    float*    bias = (float*)(w + 1048576);
    float*    xT   = (float*)(w + 1052672);
    uint32_t* P    = (uint32_t*)(w + 2101248);
    uint32_t* Yp   = (uint32_t*)(w + 18878464);

    prep_kernel<<<1024, 512, 0, stream>>>(x, W_hh, b_ih, b_hh, Wh, Wl, bias, xT, P, Yp);
    rnn_kernel<<<NBLK, NTHR, 0, stream>>>(xT, W_ih, b_fc, W_fc, Wh, Wl, bias, P, Yp, out);
}